// Round 9
// baseline (404.930 us; speedup 1.0000x reference)
//
#include <hip/hip_runtime.h>

typedef unsigned short ushort_t;
typedef __attribute__((ext_vector_type(8))) short short8;
typedef __attribute__((ext_vector_type(4))) ushort_t ushort4_t;
typedef __attribute__((ext_vector_type(4))) float f32x4;

#define Bb 2
#define Ss 2048
#define HID 2048
#define NH 16
#define NKV 4
#define Dd 128
constexpr float EPS_ = 1e-6f;
constexpr float THETA_ = 1000000.0f;
constexpr float SCALE_ = 0.08838834764831845f; // 128^-0.5
constexpr float C2_ = 0.12753785f;             // SCALE * log2(e)
constexpr float THR_RAW_ = 23.5f;              // 3 / C2_: defer-max threshold (P <= 8)

__device__ __forceinline__ ushort_t f2bf(float x) {
  union { float f; unsigned u; } v; v.f = x;
  unsigned r = (v.u + 0x7fffu + ((v.u >> 16) & 1u)) >> 16;
  return (ushort_t)r;
}
__device__ __forceinline__ float bf2f(ushort_t u) {
  union { unsigned u; float f; } v; v.u = ((unsigned)u) << 16;
  return v.f;
}

typedef const __attribute__((address_space(1))) void* gas1_t;
typedef __attribute__((address_space(3))) void* las3_t;
__device__ __forceinline__ void gload_lds16(const void* g, void* l) {
  __builtin_amdgcn_global_load_lds((gas1_t)g, (las3_t)l, 16, 0, 0);
}

__device__ __forceinline__ void store_out(float* p, float v) { *p = v; }
__device__ __forceinline__ void store_out(ushort_t* p, float v) { *p = f2bf(v); }

// ---------------- fp32 -> bf16 straight convert (8 elems/thread) ----------------
__global__ __launch_bounds__(256) void convert_f32_bf16(
    const float* __restrict__ src, ushort_t* __restrict__ dst, long n) {
  long i = ((long)blockIdx.x * 256 + threadIdx.x) * 8;
  if (i + 7 < n) {
    float4 v0 = *(const float4*)(src + i);
    float4 v1 = *(const float4*)(src + i + 4);
    ushort4_t a, b;
    a[0] = f2bf(v0.x); a[1] = f2bf(v0.y); a[2] = f2bf(v0.z); a[3] = f2bf(v0.w);
    b[0] = f2bf(v1.x); b[1] = f2bf(v1.y); b[2] = f2bf(v1.z); b[3] = f2bf(v1.w);
    *(ushort4_t*)(dst + i) = a;
    *(ushort4_t*)(dst + i + 4) = b;
  }
}

// ------- merged weight transposes: fp32 (R x C) -> bf16 (C x R), 4 weights -------
__global__ __launch_bounds__(256) void transpose_weights(
    const float* __restrict__ Wq, const float* __restrict__ Wk,
    const float* __restrict__ Wv, const float* __restrict__ Wo,
    ushort_t* __restrict__ WqkvT, ushort_t* __restrict__ WoT) {
  __shared__ float tile[32][33];
  unsigned id = blockIdx.x;
  const float* src;
  ushort_t* dst;
  int C, tX;
  if (id < 4096u) {
    src = Wq; dst = WqkvT; C = 2048; tX = 64;
  } else if (id < 5120u) {
    id -= 4096u; src = Wk; dst = WqkvT + (long)2048 * 2048; C = 512; tX = 16;
  } else if (id < 6144u) {
    id -= 5120u; src = Wv; dst = WqkvT + (long)2560 * 2048; C = 512; tX = 16;
  } else {
    id -= 6144u; src = Wo; dst = WoT; C = 2048; tX = 64;
  }
  const int R = 2048;
  int c0 = (id % tX) * 32, r0 = (id / tX) * 32;
  int tx = threadIdx.x & 31, ty = threadIdx.x >> 5; // ty 0..7
#pragma unroll
  for (int j = 0; j < 4; j++)
    tile[ty + j * 8][tx] = src[(long)(r0 + ty + j * 8) * C + c0 + tx];
  __syncthreads();
#pragma unroll
  for (int j = 0; j < 4; j++)
    dst[(long)(c0 + ty + j * 8) * R + r0 + tx] = f2bf(tile[tx][ty + j * 8]);
}

// ---------------- bf16 GEMM: C[M,N] = A[M,K] * Bt[N,K]^T ----------------
// m97 recipe: 128x128x32 tiles, 4 waves each 64x64. Kept for GEMM2.
template <typename OutT>
__global__ __launch_bounds__(256) void gemm_bt(
    const ushort_t* __restrict__ A, const ushort_t* __restrict__ Bt,
    OutT* __restrict__ C, int M, int N, int K) {
  __shared__ __align__(16) ushort_t As[128 * 32];
  __shared__ __align__(16) ushort_t Bs[128 * 32];
  const int t = threadIdx.x;
  const int wave = t >> 6, lane = t & 63;
  const int wr = wave >> 1, wc = wave & 1;
  const int quad = lane >> 4, l16 = lane & 15;

  unsigned gx = gridDim.x;
  unsigned nwg = gx * gridDim.y;
  unsigned lin = blockIdx.y * gx + blockIdx.x;
  if ((nwg & 7u) == 0u) {
    unsigned cpx = nwg >> 3;
    lin = (lin & 7u) * cpx + (lin >> 3);
  }
  const long bm = (long)(lin / gx) * 128;
  const long bn = (long)(lin % gx) * 128;

  f32x4 acc[4][4] = {};

  const int srow = t >> 2, schunk = t & 3;
  const ushort_t* aSrc = A + (bm + srow) * (long)K + schunk * 8;
  const ushort_t* bSrc = Bt + (bn + srow) * (long)K + schunk * 8;
  const int ldsOff = srow * 32 + schunk * 8;

  for (int k0 = 0; k0 < K; k0 += 32) {
    __syncthreads();
    gload_lds16(aSrc + k0, &As[ldsOff]);
    gload_lds16(aSrc + (long)64 * K + k0, &As[ldsOff + 64 * 32]);
    gload_lds16(bSrc + k0, &Bs[ldsOff]);
    gload_lds16(bSrc + (long)64 * K + k0, &Bs[ldsOff + 64 * 32]);
    __syncthreads();
    short8 af[4], bf[4];
#pragma unroll
    for (int i = 0; i < 4; i++) {
      af[i] = *(const short8*)&As[(wr * 64 + i * 16 + l16) * 32 + quad * 8];
      bf[i] = *(const short8*)&Bs[(wc * 64 + i * 16 + l16) * 32 + quad * 8];
    }
#pragma unroll
    for (int i = 0; i < 4; i++)
#pragma unroll
      for (int j = 0; j < 4; j++)
        acc[i][j] = __builtin_amdgcn_mfma_f32_16x16x32_bf16(af[i], bf[j], acc[i][j], 0, 0, 0);
  }
#pragma unroll
  for (int i = 0; i < 4; i++)
#pragma unroll
    for (int j = 0; j < 4; j++)
#pragma unroll
      for (int r = 0; r < 4; r++) {
        long rr = bm + wr * 64 + i * 16 + quad * 4 + r;
        long cc = bn + wc * 64 + j * 16 + l16;
        store_out(&C[rr * N + cc], acc[i][j][r]);
      }
}

// ---------------- 256x256 8-phase bf16 GEMM (T3+T4+T5), R7-verified ----------------
template <typename OutT>
__global__ __launch_bounds__(512) void gemm256_bt(
    const ushort_t* __restrict__ A, const ushort_t* __restrict__ Bt,
    OutT* __restrict__ C, int M, int N, int K) {
  __shared__ __align__(16) ushort_t As[2][256 * 64];
  __shared__ __align__(16) ushort_t Bs[2][256 * 64];
  const int t = threadIdx.x;
  const int wave = t >> 6, lane = t & 63;
  const int wm = wave >> 2, wn = wave & 3;
  const int quad = lane >> 4, l16 = lane & 15;

  unsigned gx = gridDim.x;
  unsigned nwg = gx * gridDim.y;
  unsigned lin = blockIdx.y * gx + blockIdx.x;
  if ((nwg & 7u) == 0u) {
    unsigned cpx = nwg >> 3;
    lin = (lin & 7u) * cpx + (lin >> 3);
  }
  const long bm = (long)(lin / gx) * 256;
  const long bn = (long)(lin % gx) * 256;

  auto stageA = [&](int kt, int ih, int bi) {
    const int k0 = kt * 64;
#pragma unroll
    for (int it = 0; it < 2; it++) {
      int ci = t + it * 512;
      int lr = ci >> 3, cl = ci & 7;
      int row = ((lr & 64) << 1) | (ih << 6) | (lr & 63);
      int cg = cl ^ (row & 7);
      gload_lds16(A + (bm + row) * (long)K + k0 + cg * 8, &As[bi][row * 64 + cl * 8]);
    }
  };
  auto stageB = [&](int kt, int jh, int bi) {
    const int k0 = kt * 64;
#pragma unroll
    for (int it = 0; it < 2; it++) {
      int ci = t + it * 512;
      int lr = ci >> 3, cl = ci & 7;
      int row = ((lr & 96) << 1) | (jh << 5) | (lr & 31);
      int cg = cl ^ (row & 7);
      gload_lds16(Bt + (bn + row) * (long)K + k0 + cg * 8, &Bs[bi][row * 64 + cl * 8]);
    }
  };

  f32x4 acc[8][4] = {};
  short8 af[2][4], bf0[2][2], bf1[2][2];

  const int nt = K >> 6;
  stageA(0, 0, 0); stageA(0, 1, 0); stageB(0, 0, 0); stageB(0, 1, 0);
  stageA(1, 0, 1); stageB(1, 0, 1);
  asm volatile("s_waitcnt vmcnt(4)" ::: "memory");
  __builtin_amdgcn_sched_barrier(0);
  __builtin_amdgcn_s_barrier();
  __builtin_amdgcn_sched_barrier(0);

  const int raBase = (wm * 128 + l16) * 64;
  const int rbBase = (wn * 64 + l16) * 64;
  const int sw = l16 & 7;

  for (int ti = 0; ti < nt; ti++) {
    const int cb = ti & 1;
    const ushort_t* as_ = As[cb];
    const ushort_t* bs_ = Bs[cb];

    // ---- phase 0
#pragma unroll
    for (int kk = 0; kk < 2; kk++) {
      int ch = ((kk * 4 + quad) ^ sw) * 8;
#pragma unroll
      for (int di = 0; di < 4; di++)
        af[kk][di] = *(const short8*)&as_[raBase + di * 1024 + ch];
#pragma unroll
      for (int dj = 0; dj < 2; dj++)
        bf0[kk][dj] = *(const short8*)&bs_[rbBase + dj * 1024 + ch];
    }
    if (ti + 1 < nt) stageA(ti + 1, 1, cb ^ 1);
    __builtin_amdgcn_sched_barrier(0);
    __builtin_amdgcn_s_barrier();
    __builtin_amdgcn_sched_barrier(0);
    __builtin_amdgcn_s_setprio(1);
#pragma unroll
    for (int di = 0; di < 4; di++)
#pragma unroll
      for (int dj = 0; dj < 2; dj++)
#pragma unroll
        for (int kk = 0; kk < 2; kk++)
          acc[di][dj] = __builtin_amdgcn_mfma_f32_16x16x32_bf16(af[kk][di], bf0[kk][dj], acc[di][dj], 0, 0, 0);
    __builtin_amdgcn_s_setprio(0);
    __builtin_amdgcn_sched_barrier(0);
    __builtin_amdgcn_s_barrier();
    __builtin_amdgcn_sched_barrier(0);

    // ---- phase 1
#pragma unroll
    for (int kk = 0; kk < 2; kk++) {
      int ch = ((kk * 4 + quad) ^ sw) * 8;
#pragma unroll
      for (int dj = 0; dj < 2; dj++)
        bf1[kk][dj] = *(const short8*)&bs_[rbBase + (2 + dj) * 1024 + ch];
    }
    if (ti + 1 < nt) stageB(ti + 1, 1, cb ^ 1);
    __builtin_amdgcn_sched_barrier(0);
    __builtin_amdgcn_s_barrier();
    __builtin_amdgcn_sched_barrier(0);
    __builtin_amdgcn_s_setprio(1);
#pragma unroll
    for (int di = 0; di < 4; di++)
#pragma unroll
      for (int dj = 0; dj < 2; dj++)
#pragma unroll
        for (int kk = 0; kk < 2; kk++)
          acc[di][2 + dj] = __builtin_amdgcn_mfma_f32_16x16x32_bf16(af[kk][di], bf1[kk][dj], acc[di][2 + dj], 0, 0, 0);
    __builtin_amdgcn_s_setprio(0);
    __builtin_amdgcn_sched_barrier(0);
    __builtin_amdgcn_s_barrier();
    __builtin_amdgcn_sched_barrier(0);

    // ---- phase 2
#pragma unroll
    for (int kk = 0; kk < 2; kk++) {
      int ch = ((kk * 4 + quad) ^ sw) * 8;
#pragma unroll
      for (int di = 0; di < 4; di++)
        af[kk][di] = *(const short8*)&as_[raBase + (4 + di) * 1024 + ch];
    }
    if (ti + 2 < nt) stageA(ti + 2, 0, cb);
    __builtin_amdgcn_sched_barrier(0);
    __builtin_amdgcn_s_barrier();
    __builtin_amdgcn_sched_barrier(0);
    __builtin_amdgcn_s_setprio(1);
#pragma unroll
    for (int di = 0; di < 4; di++)
#pragma unroll
      for (int dj = 0; dj < 2; dj++)
#pragma unroll
        for (int kk = 0; kk < 2; kk++)
          acc[4 + di][dj] = __builtin_amdgcn_mfma_f32_16x16x32_bf16(af[kk][di], bf0[kk][dj], acc[4 + di][dj], 0, 0, 0);
    __builtin_amdgcn_s_setprio(0);
    __builtin_amdgcn_sched_barrier(0);
    __builtin_amdgcn_s_barrier();
    __builtin_amdgcn_sched_barrier(0);

    // ---- phase 3
    if (ti + 2 < nt) stageB(ti + 2, 0, cb);
    __builtin_amdgcn_sched_barrier(0);
    __builtin_amdgcn_s_barrier();
    __builtin_amdgcn_sched_barrier(0);
    __builtin_amdgcn_s_setprio(1);
#pragma unroll
    for (int di = 0; di < 4; di++)
#pragma unroll
      for (int dj = 0; dj < 2; dj++)
#pragma unroll
        for (int kk = 0; kk < 2; kk++)
          acc[4 + di][2 + dj] = __builtin_amdgcn_mfma_f32_16x16x32_bf16(af[kk][di], bf1[kk][dj], acc[4 + di][2 + dj], 0, 0, 0);
    __builtin_amdgcn_s_setprio(0);
    if (ti + 2 < nt) {
      asm volatile("s_waitcnt vmcnt(4)" ::: "memory");
    } else if (ti + 1 < nt) {
      asm volatile("s_waitcnt vmcnt(0)" ::: "memory");
    }
    __builtin_amdgcn_sched_barrier(0);
    __builtin_amdgcn_s_barrier();
    __builtin_amdgcn_sched_barrier(0);
  }

#pragma unroll
  for (int i = 0; i < 8; i++)
#pragma unroll
    for (int j = 0; j < 4; j++)
#pragma unroll
      for (int r = 0; r < 4; r++) {
        long rr = bm + wm * 128 + i * 16 + quad * 4 + r;
        long cc = bn + wn * 64 + j * 16 + l16;
        store_out(&C[rr * N + cc], acc[i][j][r]);
      }
}

// ------ merged RMSNorm+RoPE (in place, Q/K heads) + V transpose ------
__global__ __launch_bounds__(256) void rmsnorm_rope_tv(
    ushort_t* __restrict__ qkv, const int* __restrict__ positions,
    const float* __restrict__ qw, const float* __restrict__ kw,
    ushort_t* __restrict__ Vt) {
  __shared__ ushort_t tile[64][65];
  unsigned bx = blockIdx.x;
  if (bx < 20480u) {
    int gw = bx * 4 + (threadIdx.x >> 6);
    int lane = threadIdx.x & 63;
    int bs = gw / 20, h = gw % 20;
    ushort_t* src = qkv + (long)bs * 3072 + h * 128;
    float x0 = bf2f(src[lane]), x1 = bf2f(src[lane + 64]);
    float ss = x0 * x0 + x1 * x1;
#pragma unroll
    for (int off = 32; off; off >>= 1) ss += __shfl_xor(ss, off);
    float r = rsqrtf(ss * (1.0f / 128.0f) + EPS_);
    const float* w = (h < 16) ? qw : kw;
    x0 = x0 * r * w[lane];
    x1 = x1 * r * w[lane + 64];
    float pos = (float)positions[bs];
    float inv_freq = powf(THETA_, -(float)lane * (1.0f / 64.0f));
    float f = pos * inv_freq;
    float sn, cs;
    sincosf(f, &sn, &cs);
    float o0 = x0 * cs - x1 * sn;
    float o1 = x1 * cs + x0 * sn;
    src[lane] = f2bf(o0);
    src[lane + 64] = f2bf(o1);
  } else {
    unsigned id = bx - 20480u;           // old grid dim3(32, 2, 8)
    int bxo = id & 31, byo = (id >> 5) & 1, bh = id >> 6;
    int s0 = bxo * 64, d0 = byo * 64;
    int b = bh >> 2, hk = bh & 3;
    int tx = threadIdx.x & 63, ty = threadIdx.x >> 6; // ty 0..3
#pragma unroll
    for (int j = 0; j < 16; j++) {
      int sl = j * 4 + ty;
      tile[sl][tx] = qkv[(long)(b * Ss + s0 + sl) * 3072 + 2560 + hk * 128 + d0 + tx];
    }
    __syncthreads();
    const long vtbase = (long)bh * Dd * Ss;
#pragma unroll
    for (int j = 0; j < 16; j++) {
      int dl = j * 4 + ty;
      Vt[vtbase + (long)(d0 + dl) * Ss + s0 + tx] = tile[tx][dl];
    }
  }
}

// ---------------- flash attention ----------------
// R9: 4 waves x 32 Q-rows (two 16-row groups/wave) instead of 8 waves x 16.
// Rationale: per K-tile each wave reads the FULL 16KB K and V tiles from LDS;
// 8 waves => 256KB LDS reads/block-iter = 4.2GB total = 61us floor at the
// 69 TB/s LDS ceiling (the real cap behind 85us, MfmaUtil 34 / VALU 44).
// With 4 waves each kfr/bfr fragment feeds TWO MFMAs (one per Q-group):
// LDS reads halve (floor ~30us); MFMA/VALU totals unchanged.
// All verified layouts bit-identical (staging swizzle, S^T map, P-store
// addressing with Ps slot = wave*2+g, defer-max, epilogue).
__global__ __launch_bounds__(256) void flash_attn(
    const ushort_t* __restrict__ qkv, const ushort_t* __restrict__ Vt,
    ushort_t* __restrict__ ctx) {
  __shared__ __align__(16) ushort_t Ks[2][64 * 128];   // [kvrow][d] (16 chunks/row)
  __shared__ __align__(16) ushort_t Vs[2][128 * 64];   // [d][kv]    (8 chunks/row)
  __shared__ __align__(16) ushort_t Ps[8][16 * 64];    // per (wave,group) P [q][key]
  const int qt = blockIdx.x, h = blockIdx.y, b = blockIdx.z;
  const int hk = h >> 2;
  const int t = threadIdx.x, wave = t >> 6, lane = t & 63;
  const int quad = lane >> 4, l16 = lane & 15;

  const ushort_t* qp = qkv + (long)(b * Ss + qt * 128) * 3072 + h * 128;
  const ushort_t* kp = qkv + (long)(b * Ss) * 3072 + 2048 + hk * 128;
  const ushort_t* vp = Vt + ((long)(b * NKV + hk) * Dd) * Ss;

  // staging with 256 threads: 4 chunks each for K and V
  auto stage = [&](int kt, int bi) {
    const int k0 = kt * 64;
#pragma unroll
    for (int it = 0; it < 4; it++) {
      int tt = t + it * 256;
      int row = tt >> 4, cl = tt & 15, cg = cl ^ (row & 15);
      gload_lds16(kp + (long)(k0 + row) * 3072 + cg * 8, &Ks[bi][tt * 8]);
    }
#pragma unroll
    for (int it = 0; it < 4; it++) {
      int tt = t + it * 256;
      int row = tt >> 3, cl = tt & 7, cg = cl ^ (row & 7);
      gload_lds16(vp + (long)row * Ss + k0 + cg * 8, &Vs[bi][tt * 8]);
    }
  };

  stage(0, 0);

  // Q fragments for both groups (rows wave*32 + g*16 + l16)
  short8 qf0[4], qf1[4];
  {
    const ushort_t* qrow0 = qp + (long)(wave * 32 + l16) * 3072 + quad * 8;
    const ushort_t* qrow1 = qrow0 + (long)16 * 3072;
#pragma unroll
    for (int kc = 0; kc < 4; kc++) {
      qf0[kc] = *(const short8*)(qrow0 + kc * 32);
      qf1[kc] = *(const short8*)(qrow1 + kc * 32);
    }
  }

  float m0 = -1e30f, m1 = -1e30f;
  float l0 = 0.f, l1 = 0.f;
  f32x4 o0[8] = {}, o1[8] = {};

  asm volatile("s_waitcnt vmcnt(0)" ::: "memory");
  __syncthreads();

  const int ps0 = wave * 2, ps1 = wave * 2 + 1;

  int cur = 0;
  for (int kt = 0; kt < Ss / 64; kt++) {
    if (kt + 1 < Ss / 64) stage(kt + 1, cur ^ 1);

    // S^T for both groups: one kfr read feeds two MFMAs
    f32x4 sa0[4] = {}, sa1[4] = {};
    __builtin_amdgcn_s_setprio(1);
#pragma unroll
    for (int kc = 0; kc < 4; kc++) {
#pragma unroll
      for (int nt = 0; nt < 4; nt++) {
        int brow = nt * 16 + l16;
        short8 kfr = *(const short8*)&Ks[cur][brow * 128 + (((kc * 4 + quad) ^ (brow & 15)) * 8)];
        sa0[nt] = __builtin_amdgcn_mfma_f32_16x16x32_bf16(kfr, qf0[kc], sa0[nt], 0, 0, 0);
        sa1[nt] = __builtin_amdgcn_mfma_f32_16x16x32_bf16(kfr, qf1[kc], sa1[nt], 0, 0, 0);
      }
    }
    __builtin_amdgcn_s_setprio(0);

    // group 0 softmax
    {
      float pmax = sa0[0][0];
#pragma unroll
      for (int nt = 0; nt < 4; nt++)
#pragma unroll
        for (int r = 0; r < 4; r++) pmax = fmaxf(pmax, sa0[nt][r]);
      bool upd = __any(pmax > m0 + THR_RAW_);
      float alpha = 1.0f;
      if (upd) {
        float mx = fmaxf(pmax, __shfl_xor(pmax, 16));
        mx = fmaxf(mx, __shfl_xor(mx, 32));
        float mnew = fmaxf(m0, mx);
        alpha = __builtin_amdgcn_exp2f((m0 - mnew) * C2_);
        m0 = mnew;
        l0 *= alpha;
      }
      float mC2 = m0 * C2_;
      float rs = 0.f;
#pragma unroll
      for (int nt = 0; nt < 4; nt++) {
        int cbase = l16 * 64 + ((nt * 2 + (quad >> 1)) ^ (l16 & 7)) * 8 + (quad & 1) * 4;
#pragma unroll
        for (int r = 0; r < 4; r++) {
          float p = __builtin_amdgcn_exp2f(__builtin_fmaf(sa0[nt][r], C2_, -mC2));
          rs += p;
          union { float f; unsigned u; } pv; pv.f = p;
          Ps[ps0][cbase + r] = (ushort_t)((pv.u + 0x8000u) >> 16);
        }
      }
      l0 += rs;
      if (upd) {
        float ar0 = __shfl(alpha, quad * 4 + 0);
        float ar1 = __shfl(alpha, quad * 4 + 1);
        float ar2 = __shfl(alpha, quad * 4 + 2);
        float ar3 = __shfl(alpha, quad * 4 + 3);
#pragma unroll
        for (int dt = 0; dt < 8; dt++) {
          o0[dt][0] *= ar0; o0[dt][1] *= ar1; o0[dt][2] *= ar2; o0[dt][3] *= ar3;
        }
      }
    }
    // group 1 softmax
    {
      float pmax = sa1[0][0];
#pragma unroll
      for (int nt = 0; nt < 4; nt++)
#pragma unroll
        for (int r = 0; r < 4; r++) pmax = fmaxf(pmax, sa1[nt][r]);
      bool upd = __any(pmax > m1 + THR_RAW_);
      float alpha = 1.0f;
      if (upd) {
        float mx = fmaxf(pmax, __shfl_xor(pmax, 16));
        mx = fmaxf(mx, __shfl_xor(mx, 32));
        float mnew = fmaxf(m1, mx);
        alpha = __builtin_amdgcn_exp2f((m1 - mnew) * C2_);
        m1 = mnew;
        l1 *= alpha;
      }
      float mC2 = m1 * C2_;
      float rs = 0.f;
#pragma unroll
      for (int nt = 0; nt < 4; nt++) {
        int cbase = l16 * 64 + ((nt * 2 + (quad >> 1)) ^ (l16 & 7)) * 8 + (quad & 1) * 4;
#pragma unroll
        for (int r = 0; r < 4; r++) {
          float p = __builtin_amdgcn_exp2f(__builtin_fmaf(sa1[nt][r], C2_, -mC2));
          rs += p;
          union { float f; unsigned u; } pv; pv.f = p;
          Ps[ps1][cbase + r] = (ushort_t)((pv.u + 0x8000u) >> 16);
        }
      }
      l1 += rs;
      if (upd) {
        float ar0 = __shfl(alpha, quad * 4 + 0);
        float ar1 = __shfl(alpha, quad * 4 + 1);
        float ar2 = __shfl(alpha, quad * 4 + 2);
        float ar3 = __shfl(alpha, quad * 4 + 3);
#pragma unroll
        for (int dt = 0; dt < 8; dt++) {
          o1[dt][0] *= ar0; o1[dt][1] *= ar1; o1[dt][2] *= ar2; o1[dt][3] *= ar3;
        }
      }
    }
    asm volatile("s_waitcnt lgkmcnt(0)" ::: "memory");

    // O += P V: one bfr read feeds two MFMAs
    __builtin_amdgcn_s_setprio(1);
#pragma unroll
    for (int kc = 0; kc < 2; kc++) {
      int aoff = l16 * 64 + (((kc * 4 + quad) ^ (l16 & 7)) * 8);
      short8 af0 = *(const short8*)&Ps[ps0][aoff];
      short8 af1 = *(const short8*)&Ps[ps1][aoff];
#pragma unroll
      for (int dt = 0; dt < 8; dt++) {
        int brow = dt * 16 + l16;
        short8 bfr = *(const short8*)&Vs[cur][brow * 64 + (((kc * 4 + quad) ^ (brow & 7)) * 8)];
        o0[dt] = __builtin_amdgcn_mfma_f32_16x16x32_bf16(af0, bfr, o0[dt], 0, 0, 0);
        o1[dt] = __builtin_amdgcn_mfma_f32_16x16x32_bf16(af1, bfr, o1[dt], 0, 0, 0);
      }
    }
    __builtin_amdgcn_s_setprio(0);

    asm volatile("s_waitcnt vmcnt(0)" ::: "memory");
    __syncthreads();
    cur ^= 1;
  }

  // epilogue, both groups
  const long ldc = NH * Dd;
  {
    float lt = l0 + __shfl_xor(l0, 16);
    lt += __shfl_xor(lt, 32);
    float linv = 1.0f / lt;
    float lr0 = __shfl(linv, quad * 4 + 0);
    float lr1 = __shfl(linv, quad * 4 + 1);
    float lr2 = __shfl(linv, quad * 4 + 2);
    float lr3 = __shfl(linv, quad * 4 + 3);
    const long obase = (long)(b * Ss + qt * 128 + wave * 32) * ldc + h * Dd;
#pragma unroll
    for (int dt = 0; dt < 8; dt++) {
      int col = dt * 16 + l16;
      ctx[obase + (long)(quad * 4 + 0) * ldc + col] = f2bf(o0[dt][0] * lr0);
      ctx[obase + (long)(quad * 4 + 1) * ldc + col] = f2bf(o0[dt][1] * lr1);
      ctx[obase + (long)(quad * 4 + 2) * ldc + col] = f2bf(o0[dt][2] * lr2);
      ctx[obase + (long)(quad * 4 + 3) * ldc + col] = f2bf(o0[dt][3] * lr3);
    }
  }
  {
    float lt = l1 + __shfl_xor(l1, 16);
    lt += __shfl_xor(lt, 32);
    float linv = 1.0f / lt;
    float lr0 = __shfl(linv, quad * 4 + 0);
    float lr1 = __shfl(linv, quad * 4 + 1);
    float lr2 = __shfl(linv, quad * 4 + 2);
    float lr3 = __shfl(linv, quad * 4 + 3);
    const long obase = (long)(b * Ss + qt * 128 + wave * 32 + 16) * ldc + h * Dd;
#pragma unroll
    for (int dt = 0; dt < 8; dt++) {
      int col = dt * 16 + l16;
      ctx[obase + (long)(quad * 4 + 0) * ldc + col] = f2bf(o1[dt][0] * lr0);
      ctx[obase + (long)(quad * 4 + 1) * ldc + col] = f2bf(o1[dt][1] * lr1);
      ctx[obase + (long)(quad * 4 + 2) * ldc + col] = f2bf(o1[dt][2] * lr2);
      ctx[obase + (long)(quad * 4 + 3) * ldc + col] = f2bf(o1[dt][3] * lr3);
    }
  }
}

extern "C" void kernel_launch(void* const* d_in, const int* in_sizes, int n_in,
                              void* d_out, int out_size, void* d_ws, size_t ws_size,
                              hipStream_t stream) {
  const float* hidden = (const float*)d_in[0];
  const int* positions = (const int*)d_in[1];
  const float* Wq = (const float*)d_in[2];
  const float* Wk = (const float*)d_in[3];
  const float* Wv = (const float*)d_in[4];
  const float* Wo = (const float*)d_in[5];
  const float* qw = (const float*)d_in[6];
  const float* kw = (const float*)d_in[7];
  float* out = (float*)d_out;

  // 64 MB workspace layout:
  char* ws = (char*)d_ws;
  ushort_t* Xbf = (ushort_t*)(ws);                    // 16 MB (4096x2048 bf16)
  ushort_t* WqkvT = (ushort_t*)(ws + (16l << 20));    // 12 MB (3072x2048 bf16)
  ushort_t* WoT = (ushort_t*)(ws + (28l << 20));      //  8 MB (2048x2048 bf16)
  ushort_t* qkvb = (ushort_t*)(ws + (36l << 20));     // 24 MB (4096x3072 bf16)
  ushort_t* Vt = (ushort_t*)(ws + (60l << 20));       //  4 MB (B,NKV,D,S bf16)
  ushort_t* ctx = Xbf;                                // reuse (dead after GEMM1)

  const long nX = (long)Bb * Ss * HID;
  convert_f32_bf16<<<(unsigned)(nX / 8 / 256), 256, 0, stream>>>(hidden, Xbf, nX);
  transpose_weights<<<10240, 256, 0, stream>>>(Wq, Wk, Wv, Wo, WqkvT, WoT);

  // GEMM1 on the 8-phase 256^2 kernel: grid 12x16 = 192 blocks (%8==0)
  gemm256_bt<ushort_t><<<dim3(3072 / 256, 4096 / 256), 512, 0, stream>>>(Xbf, WqkvT, qkvb, 4096, 3072, 2048);

  rmsnorm_rope_tv<<<20480 + 512, 256, 0, stream>>>(qkvb, positions, qw, kw, Vt);

  flash_attn<<<dim3(Ss / 128, NH, Bb), 256, 0, stream>>>(qkvb, Vt, ctx);

  gemm_bt<float><<<dim3(2048 / 128, 4096 / 128), 256, 0, stream>>>(ctx, WoT, out, 4096, 2048, 2048);
}

// Round 10
// 335.785 us; speedup vs baseline: 1.2059x; 1.2059x over previous
//
#include <hip/hip_runtime.h>

typedef unsigned short ushort_t;
typedef __attribute__((ext_vector_type(8))) short short8;
typedef __attribute__((ext_vector_type(4))) ushort_t ushort4_t;
typedef __attribute__((ext_vector_type(4))) float f32x4;

#define Bb 2
#define Ss 2048
#define HID 2048
#define NH 16
#define NKV 4
#define Dd 128
constexpr float EPS_ = 1e-6f;
constexpr float THETA_ = 1000000.0f;
constexpr float SCALE_ = 0.08838834764831845f; // 128^-0.5
constexpr float C2_ = 0.12753785f;             // SCALE * log2(e)
constexpr float THR_RAW_ = 23.5f;              // 3 / C2_: defer-max threshold (P <= 8)

__device__ __forceinline__ ushort_t f2bf(float x) {
  union { float f; unsigned u; } v; v.f = x;
  unsigned r = (v.u + 0x7fffu + ((v.u >> 16) & 1u)) >> 16;
  return (ushort_t)r;
}
__device__ __forceinline__ float bf2f(ushort_t u) {
  union { unsigned u; float f; } v; v.u = ((unsigned)u) << 16;
  return v.f;
}

typedef const __attribute__((address_space(1))) void* gas1_t;
typedef __attribute__((address_space(3))) void* las3_t;
__device__ __forceinline__ void gload_lds16(const void* g, void* l) {
  __builtin_amdgcn_global_load_lds((gas1_t)g, (las3_t)l, 16, 0, 0);
}

__device__ __forceinline__ void store_out(float* p, float v) { *p = v; }
__device__ __forceinline__ void store_out(ushort_t* p, float v) { *p = f2bf(v); }

// ------- merged input prep: X fp32->bf16 convert + 4 weight transposes -------
// blocks [0,4096): convert hidden (8 elems/thread)
// blocks [4096,14336): weight transpose tiles
//   [4096,8192) Wq | [8192,9216) Wk | [9216,10240) Wv | [10240,14336) Wo
__global__ __launch_bounds__(256) void prep_inputs(
    const float* __restrict__ hidden, ushort_t* __restrict__ Xbf,
    const float* __restrict__ Wq, const float* __restrict__ Wk,
    const float* __restrict__ Wv, const float* __restrict__ Wo,
    ushort_t* __restrict__ WqkvT, ushort_t* __restrict__ WoT) {
  __shared__ float tile[32][33];
  unsigned id = blockIdx.x;
  if (id < 4096u) {
    long i = ((long)id * 256 + threadIdx.x) * 8;
    float4 v0 = *(const float4*)(hidden + i);
    float4 v1 = *(const float4*)(hidden + i + 4);
    ushort4_t a, b;
    a[0] = f2bf(v0.x); a[1] = f2bf(v0.y); a[2] = f2bf(v0.z); a[3] = f2bf(v0.w);
    b[0] = f2bf(v1.x); b[1] = f2bf(v1.y); b[2] = f2bf(v1.z); b[3] = f2bf(v1.w);
    *(ushort4_t*)(Xbf + i) = a;
    *(ushort4_t*)(Xbf + i + 4) = b;
    return;
  }
  id -= 4096u;
  const float* src;
  ushort_t* dst;
  int C, tX;
  if (id < 4096u) {
    src = Wq; dst = WqkvT; C = 2048; tX = 64;
  } else if (id < 5120u) {
    id -= 4096u; src = Wk; dst = WqkvT + (long)2048 * 2048; C = 512; tX = 16;
  } else if (id < 6144u) {
    id -= 5120u; src = Wv; dst = WqkvT + (long)2560 * 2048; C = 512; tX = 16;
  } else {
    id -= 6144u; src = Wo; dst = WoT; C = 2048; tX = 64;
  }
  const int R = 2048;
  int c0 = (id % tX) * 32, r0 = (id / tX) * 32;
  int tx = threadIdx.x & 31, ty = threadIdx.x >> 5; // ty 0..7
#pragma unroll
  for (int j = 0; j < 4; j++)
    tile[ty + j * 8][tx] = src[(long)(r0 + ty + j * 8) * C + c0 + tx];
  __syncthreads();
#pragma unroll
  for (int j = 0; j < 4; j++)
    dst[(long)(c0 + ty + j * 8) * R + r0 + tx] = f2bf(tile[tx][ty + j * 8]);
}

// ---------------- bf16 GEMM: C[M,N] = A[M,K] * Bt[N,K]^T ----------------
// m97 recipe: 128x128x32 tiles, 4 waves each 64x64. Kept for GEMM2.
template <typename OutT>
__global__ __launch_bounds__(256) void gemm_bt(
    const ushort_t* __restrict__ A, const ushort_t* __restrict__ Bt,
    OutT* __restrict__ C, int M, int N, int K) {
  __shared__ __align__(16) ushort_t As[128 * 32];
  __shared__ __align__(16) ushort_t Bs[128 * 32];
  const int t = threadIdx.x;
  const int wave = t >> 6, lane = t & 63;
  const int wr = wave >> 1, wc = wave & 1;
  const int quad = lane >> 4, l16 = lane & 15;

  unsigned gx = gridDim.x;
  unsigned nwg = gx * gridDim.y;
  unsigned lin = blockIdx.y * gx + blockIdx.x;
  if ((nwg & 7u) == 0u) {
    unsigned cpx = nwg >> 3;
    lin = (lin & 7u) * cpx + (lin >> 3);
  }
  const long bm = (long)(lin / gx) * 128;
  const long bn = (long)(lin % gx) * 128;

  f32x4 acc[4][4] = {};

  const int srow = t >> 2, schunk = t & 3;
  const ushort_t* aSrc = A + (bm + srow) * (long)K + schunk * 8;
  const ushort_t* bSrc = Bt + (bn + srow) * (long)K + schunk * 8;
  const int ldsOff = srow * 32 + schunk * 8;

  for (int k0 = 0; k0 < K; k0 += 32) {
    __syncthreads();
    gload_lds16(aSrc + k0, &As[ldsOff]);
    gload_lds16(aSrc + (long)64 * K + k0, &As[ldsOff + 64 * 32]);
    gload_lds16(bSrc + k0, &Bs[ldsOff]);
    gload_lds16(bSrc + (long)64 * K + k0, &Bs[ldsOff + 64 * 32]);
    __syncthreads();
    short8 af[4], bf[4];
#pragma unroll
    for (int i = 0; i < 4; i++) {
      af[i] = *(const short8*)&As[(wr * 64 + i * 16 + l16) * 32 + quad * 8];
      bf[i] = *(const short8*)&Bs[(wc * 64 + i * 16 + l16) * 32 + quad * 8];
    }
#pragma unroll
    for (int i = 0; i < 4; i++)
#pragma unroll
      for (int j = 0; j < 4; j++)
        acc[i][j] = __builtin_amdgcn_mfma_f32_16x16x32_bf16(af[i], bf[j], acc[i][j], 0, 0, 0);
  }
#pragma unroll
  for (int i = 0; i < 4; i++)
#pragma unroll
    for (int j = 0; j < 4; j++)
#pragma unroll
      for (int r = 0; r < 4; r++) {
        long rr = bm + wr * 64 + i * 16 + quad * 4 + r;
        long cc = bn + wc * 64 + j * 16 + l16;
        store_out(&C[rr * N + cc], acc[i][j][r]);
      }
}

// ---------------- 256x256 8-phase bf16 GEMM (T3+T4+T5), R7-verified ----------------
template <typename OutT>
__global__ __launch_bounds__(512) void gemm256_bt(
    const ushort_t* __restrict__ A, const ushort_t* __restrict__ Bt,
    OutT* __restrict__ C, int M, int N, int K) {
  __shared__ __align__(16) ushort_t As[2][256 * 64];
  __shared__ __align__(16) ushort_t Bs[2][256 * 64];
  const int t = threadIdx.x;
  const int wave = t >> 6, lane = t & 63;
  const int wm = wave >> 2, wn = wave & 3;
  const int quad = lane >> 4, l16 = lane & 15;

  unsigned gx = gridDim.x;
  unsigned nwg = gx * gridDim.y;
  unsigned lin = blockIdx.y * gx + blockIdx.x;
  if ((nwg & 7u) == 0u) {
    unsigned cpx = nwg >> 3;
    lin = (lin & 7u) * cpx + (lin >> 3);
  }
  const long bm = (long)(lin / gx) * 256;
  const long bn = (long)(lin % gx) * 256;

  auto stageA = [&](int kt, int ih, int bi) {
    const int k0 = kt * 64;
#pragma unroll
    for (int it = 0; it < 2; it++) {
      int ci = t + it * 512;
      int lr = ci >> 3, cl = ci & 7;
      int row = ((lr & 64) << 1) | (ih << 6) | (lr & 63);
      int cg = cl ^ (row & 7);
      gload_lds16(A + (bm + row) * (long)K + k0 + cg * 8, &As[bi][row * 64 + cl * 8]);
    }
  };
  auto stageB = [&](int kt, int jh, int bi) {
    const int k0 = kt * 64;
#pragma unroll
    for (int it = 0; it < 2; it++) {
      int ci = t + it * 512;
      int lr = ci >> 3, cl = ci & 7;
      int row = ((lr & 96) << 1) | (jh << 5) | (lr & 31);
      int cg = cl ^ (row & 7);
      gload_lds16(Bt + (bn + row) * (long)K + k0 + cg * 8, &Bs[bi][row * 64 + cl * 8]);
    }
  };

  f32x4 acc[8][4] = {};
  short8 af[2][4], bf0[2][2], bf1[2][2];

  const int nt = K >> 6;
  stageA(0, 0, 0); stageA(0, 1, 0); stageB(0, 0, 0); stageB(0, 1, 0);
  stageA(1, 0, 1); stageB(1, 0, 1);
  asm volatile("s_waitcnt vmcnt(4)" ::: "memory");
  __builtin_amdgcn_sched_barrier(0);
  __builtin_amdgcn_s_barrier();
  __builtin_amdgcn_sched_barrier(0);

  const int raBase = (wm * 128 + l16) * 64;
  const int rbBase = (wn * 64 + l16) * 64;
  const int sw = l16 & 7;

  for (int ti = 0; ti < nt; ti++) {
    const int cb = ti & 1;
    const ushort_t* as_ = As[cb];
    const ushort_t* bs_ = Bs[cb];

    // ---- phase 0
#pragma unroll
    for (int kk = 0; kk < 2; kk++) {
      int ch = ((kk * 4 + quad) ^ sw) * 8;
#pragma unroll
      for (int di = 0; di < 4; di++)
        af[kk][di] = *(const short8*)&as_[raBase + di * 1024 + ch];
#pragma unroll
      for (int dj = 0; dj < 2; dj++)
        bf0[kk][dj] = *(const short8*)&bs_[rbBase + dj * 1024 + ch];
    }
    if (ti + 1 < nt) stageA(ti + 1, 1, cb ^ 1);
    __builtin_amdgcn_sched_barrier(0);
    __builtin_amdgcn_s_barrier();
    __builtin_amdgcn_sched_barrier(0);
    __builtin_amdgcn_s_setprio(1);
#pragma unroll
    for (int di = 0; di < 4; di++)
#pragma unroll
      for (int dj = 0; dj < 2; dj++)
#pragma unroll
        for (int kk = 0; kk < 2; kk++)
          acc[di][dj] = __builtin_amdgcn_mfma_f32_16x16x32_bf16(af[kk][di], bf0[kk][dj], acc[di][dj], 0, 0, 0);
    __builtin_amdgcn_s_setprio(0);
    __builtin_amdgcn_sched_barrier(0);
    __builtin_amdgcn_s_barrier();
    __builtin_amdgcn_sched_barrier(0);

    // ---- phase 1
#pragma unroll
    for (int kk = 0; kk < 2; kk++) {
      int ch = ((kk * 4 + quad) ^ sw) * 8;
#pragma unroll
      for (int dj = 0; dj < 2; dj++)
        bf1[kk][dj] = *(const short8*)&bs_[rbBase + (2 + dj) * 1024 + ch];
    }
    if (ti + 1 < nt) stageB(ti + 1, 1, cb ^ 1);
    __builtin_amdgcn_sched_barrier(0);
    __builtin_amdgcn_s_barrier();
    __builtin_amdgcn_sched_barrier(0);
    __builtin_amdgcn_s_setprio(1);
#pragma unroll
    for (int di = 0; di < 4; di++)
#pragma unroll
      for (int dj = 0; dj < 2; dj++)
#pragma unroll
        for (int kk = 0; kk < 2; kk++)
          acc[di][2 + dj] = __builtin_amdgcn_mfma_f32_16x16x32_bf16(af[kk][di], bf1[kk][dj], acc[di][2 + dj], 0, 0, 0);
    __builtin_amdgcn_s_setprio(0);
    __builtin_amdgcn_sched_barrier(0);
    __builtin_amdgcn_s_barrier();
    __builtin_amdgcn_sched_barrier(0);

    // ---- phase 2
#pragma unroll
    for (int kk = 0; kk < 2; kk++) {
      int ch = ((kk * 4 + quad) ^ sw) * 8;
#pragma unroll
      for (int di = 0; di < 4; di++)
        af[kk][di] = *(const short8*)&as_[raBase + (4 + di) * 1024 + ch];
    }
    if (ti + 2 < nt) stageA(ti + 2, 0, cb);
    __builtin_amdgcn_sched_barrier(0);
    __builtin_amdgcn_s_barrier();
    __builtin_amdgcn_sched_barrier(0);
    __builtin_amdgcn_s_setprio(1);
#pragma unroll
    for (int di = 0; di < 4; di++)
#pragma unroll
      for (int dj = 0; dj < 2; dj++)
#pragma unroll
        for (int kk = 0; kk < 2; kk++)
          acc[4 + di][dj] = __builtin_amdgcn_mfma_f32_16x16x32_bf16(af[kk][di], bf0[kk][dj], acc[4 + di][dj], 0, 0, 0);
    __builtin_amdgcn_s_setprio(0);
    __builtin_amdgcn_sched_barrier(0);
    __builtin_amdgcn_s_barrier();
    __builtin_amdgcn_sched_barrier(0);

    // ---- phase 3
    if (ti + 2 < nt) stageB(ti + 2, 0, cb);
    __builtin_amdgcn_sched_barrier(0);
    __builtin_amdgcn_s_barrier();
    __builtin_amdgcn_sched_barrier(0);
    __builtin_amdgcn_s_setprio(1);
#pragma unroll
    for (int di = 0; di < 4; di++)
#pragma unroll
      for (int dj = 0; dj < 2; dj++)
#pragma unroll
        for (int kk = 0; kk < 2; kk++)
          acc[4 + di][2 + dj] = __builtin_amdgcn_mfma_f32_16x16x32_bf16(af[kk][di], bf1[kk][dj], acc[4 + di][2 + dj], 0, 0, 0);
    __builtin_amdgcn_s_setprio(0);
    if (ti + 2 < nt) {
      asm volatile("s_waitcnt vmcnt(4)" ::: "memory");
    } else if (ti + 1 < nt) {
      asm volatile("s_waitcnt vmcnt(0)" ::: "memory");
    }
    __builtin_amdgcn_sched_barrier(0);
    __builtin_amdgcn_s_barrier();
    __builtin_amdgcn_sched_barrier(0);
  }

#pragma unroll
  for (int i = 0; i < 8; i++)
#pragma unroll
    for (int j = 0; j < 4; j++)
#pragma unroll
      for (int r = 0; r < 4; r++) {
        long rr = bm + wm * 128 + i * 16 + quad * 4 + r;
        long cc = bn + wn * 64 + j * 16 + l16;
        store_out(&C[rr * N + cc], acc[i][j][r]);
      }
}

// ------ merged RMSNorm+RoPE (in place, Q/K heads) + V transpose ------
__global__ __launch_bounds__(256) void rmsnorm_rope_tv(
    ushort_t* __restrict__ qkv, const int* __restrict__ positions,
    const float* __restrict__ qw, const float* __restrict__ kw,
    ushort_t* __restrict__ Vt) {
  __shared__ ushort_t tile[64][65];
  unsigned bx = blockIdx.x;
  if (bx < 20480u) {
    int gw = bx * 4 + (threadIdx.x >> 6);
    int lane = threadIdx.x & 63;
    int bs = gw / 20, h = gw % 20;
    ushort_t* src = qkv + (long)bs * 3072 + h * 128;
    float x0 = bf2f(src[lane]), x1 = bf2f(src[lane + 64]);
    float ss = x0 * x0 + x1 * x1;
#pragma unroll
    for (int off = 32; off; off >>= 1) ss += __shfl_xor(ss, off);
    float r = rsqrtf(ss * (1.0f / 128.0f) + EPS_);
    const float* w = (h < 16) ? qw : kw;
    x0 = x0 * r * w[lane];
    x1 = x1 * r * w[lane + 64];
    float pos = (float)positions[bs];
    float inv_freq = powf(THETA_, -(float)lane * (1.0f / 64.0f));
    float f = pos * inv_freq;
    float sn, cs;
    sincosf(f, &sn, &cs);
    float o0 = x0 * cs - x1 * sn;
    float o1 = x1 * cs + x0 * sn;
    src[lane] = f2bf(o0);
    src[lane + 64] = f2bf(o1);
  } else {
    unsigned id = bx - 20480u;           // old grid dim3(32, 2, 8)
    int bxo = id & 31, byo = (id >> 5) & 1, bh = id >> 6;
    int s0 = bxo * 64, d0 = byo * 64;
    int b = bh >> 2, hk = bh & 3;
    int tx = threadIdx.x & 63, ty = threadIdx.x >> 6; // ty 0..3
#pragma unroll
    for (int j = 0; j < 16; j++) {
      int sl = j * 4 + ty;
      tile[sl][tx] = qkv[(long)(b * Ss + s0 + sl) * 3072 + 2560 + hk * 128 + d0 + tx];
    }
    __syncthreads();
    const long vtbase = (long)bh * Dd * Ss;
#pragma unroll
    for (int j = 0; j < 16; j++) {
      int dl = j * 4 + ty;
      Vt[vtbase + (long)(d0 + dl) * Ss + s0 + tx] = tile[tx][dl];
    }
  }
}

// ---------------- flash attention (R8 state restored: 85us, verified) ----------------
// R9 lesson: 4-wave/high-VGPR variant collapsed occupancy (VGPR 144 > 128
// step -> 8 waves/CU cap; measured 11%, 154us). This kernel must keep
// VGPR <= 64 and 8 waves/block; occupancy is the binding resource.
__global__ __launch_bounds__(512) void flash_attn(
    const ushort_t* __restrict__ qkv, const ushort_t* __restrict__ Vt,
    ushort_t* __restrict__ ctx) {
  __shared__ __align__(16) ushort_t Ks[2][64 * 128];   // [kvrow][d] (16 chunks/row)
  __shared__ __align__(16) ushort_t Vs[2][128 * 64];   // [d][kv]    (8 chunks/row)
  __shared__ __align__(16) ushort_t Ps[8][16 * 64];    // per-wave P [q][key]
  const int qt = blockIdx.x, h = blockIdx.y, b = blockIdx.z;
  const int hk = h >> 2;
  const int t = threadIdx.x, wave = t >> 6, lane = t & 63;
  const int quad = lane >> 4, l16 = lane & 15;

  const ushort_t* qp = qkv + (long)(b * Ss + qt * 128) * 3072 + h * 128;
  const ushort_t* kp = qkv + (long)(b * Ss) * 3072 + 2048 + hk * 128;
  const ushort_t* vp = Vt + ((long)(b * NKV + hk) * Dd) * Ss;

  auto stage = [&](int kt, int bi) {
    const int k0 = kt * 64;
#pragma unroll
    for (int it = 0; it < 2; it++) {
      int tt = t + it * 512;
      int row = tt >> 4, cl = tt & 15, cg = cl ^ (row & 15);
      gload_lds16(kp + (long)(k0 + row) * 3072 + cg * 8, &Ks[bi][tt * 8]);
    }
#pragma unroll
    for (int it = 0; it < 2; it++) {
      int tt = t + it * 512;
      int row = tt >> 3, cl = tt & 7, cg = cl ^ (row & 7);
      gload_lds16(vp + (long)row * Ss + k0 + cg * 8, &Vs[bi][tt * 8]);
    }
  };

  stage(0, 0);

  short8 qf[4];
  {
    const ushort_t* qrow = qp + (long)(wave * 16 + l16) * 3072 + quad * 8;
#pragma unroll
    for (int kc = 0; kc < 4; kc++)
      qf[kc] = *(const short8*)(qrow + kc * 32);
  }

  float m_i = -1e30f;   // running max for q = l16 (replicated across quads)
  float l_acc = 0.f;    // per-lane partial denom (q = l16, this quad's keys)
  f32x4 o[8] = {};      // output: q = quad*4+r, d = dt*16+l16

  asm volatile("s_waitcnt vmcnt(0)" ::: "memory");
  __syncthreads();

  int cur = 0;
  for (int kt = 0; kt < Ss / 64; kt++) {
    if (kt + 1 < Ss / 64) stage(kt + 1, cur ^ 1);

    // S^T: sa[nt][r] = S[key = nt*16 + quad*4 + r][q = l16]
    f32x4 sa[4] = {};
    __builtin_amdgcn_s_setprio(1);
#pragma unroll
    for (int kc = 0; kc < 4; kc++) {
#pragma unroll
      for (int nt = 0; nt < 4; nt++) {
        int brow = nt * 16 + l16;
        short8 kfr = *(const short8*)&Ks[cur][brow * 128 + (((kc * 4 + quad) ^ (brow & 15)) * 8)];
        sa[nt] = __builtin_amdgcn_mfma_f32_16x16x32_bf16(kfr, qf[kc], sa[nt], 0, 0, 0);
      }
    }
    __builtin_amdgcn_s_setprio(0);

    float pmax = sa[0][0];
#pragma unroll
    for (int nt = 0; nt < 4; nt++)
#pragma unroll
      for (int r = 0; r < 4; r++) pmax = fmaxf(pmax, sa[nt][r]);

    bool upd = __any(pmax > m_i + THR_RAW_);
    float alpha = 1.0f;
    if (upd) {
      float mx = fmaxf(pmax, __shfl_xor(pmax, 16));
      mx = fmaxf(mx, __shfl_xor(mx, 32));        // true row max, all quads
      float mnew = fmaxf(m_i, mx);
      alpha = __builtin_amdgcn_exp2f((m_i - mnew) * C2_);
      m_i = mnew;
      l_acc *= alpha;
    }

    float mC2 = m_i * C2_;
    float rs = 0.f;
#pragma unroll
    for (int nt = 0; nt < 4; nt++) {
      int cbase = l16 * 64 + ((nt * 2 + (quad >> 1)) ^ (l16 & 7)) * 8 + (quad & 1) * 4;
#pragma unroll
      for (int r = 0; r < 4; r++) {
        float p = __builtin_amdgcn_exp2f(__builtin_fmaf(sa[nt][r], C2_, -mC2));
        rs += p;
        union { float f; unsigned u; } pv; pv.f = p;
        Ps[wave][cbase + r] = (ushort_t)((pv.u + 0x8000u) >> 16);
      }
    }
    l_acc += rs;

    if (upd) {
      float ar0 = __shfl(alpha, quad * 4 + 0);
      float ar1 = __shfl(alpha, quad * 4 + 1);
      float ar2 = __shfl(alpha, quad * 4 + 2);
      float ar3 = __shfl(alpha, quad * 4 + 3);
#pragma unroll
      for (int dt = 0; dt < 8; dt++) {
        o[dt][0] *= ar0; o[dt][1] *= ar1; o[dt][2] *= ar2; o[dt][3] *= ar3;
      }
    }
    asm volatile("s_waitcnt lgkmcnt(0)" ::: "memory");

    __builtin_amdgcn_s_setprio(1);
#pragma unroll
    for (int kc = 0; kc < 2; kc++) {
      int arow = l16;
      short8 af = *(const short8*)&Ps[wave][arow * 64 + (((kc * 4 + quad) ^ (arow & 7)) * 8)];
#pragma unroll
      for (int dt = 0; dt < 8; dt++) {
        int brow = dt * 16 + l16;
        short8 bfr = *(const short8*)&Vs[cur][brow * 64 + (((kc * 4 + quad) ^ (brow & 7)) * 8)];
        o[dt] = __builtin_amdgcn_mfma_f32_16x16x32_bf16(af, bfr, o[dt], 0, 0, 0);
      }
    }
    __builtin_amdgcn_s_setprio(0);

    asm volatile("s_waitcnt vmcnt(0)" ::: "memory");
    __syncthreads();
    cur ^= 1;
  }

  float lt = l_acc + __shfl_xor(l_acc, 16);
  lt += __shfl_xor(lt, 32);
  float linv = 1.0f / lt;
  float lr0 = __shfl(linv, quad * 4 + 0);
  float lr1 = __shfl(linv, quad * 4 + 1);
  float lr2 = __shfl(linv, quad * 4 + 2);
  float lr3 = __shfl(linv, quad * 4 + 3);
  const long obase = (long)(b * Ss + qt * 128 + wave * 16) * (NH * Dd) + h * Dd;
#pragma unroll
  for (int dt = 0; dt < 8; dt++) {
    int col = dt * 16 + l16;
    ctx[obase + (long)(quad * 4 + 0) * (NH * Dd) + col] = f2bf(o[dt][0] * lr0);
    ctx[obase + (long)(quad * 4 + 1) * (NH * Dd) + col] = f2bf(o[dt][1] * lr1);
    ctx[obase + (long)(quad * 4 + 2) * (NH * Dd) + col] = f2bf(o[dt][2] * lr2);
    ctx[obase + (long)(quad * 4 + 3) * (NH * Dd) + col] = f2bf(o[dt][3] * lr3);
  }
}

extern "C" void kernel_launch(void* const* d_in, const int* in_sizes, int n_in,
                              void* d_out, int out_size, void* d_ws, size_t ws_size,
                              hipStream_t stream) {
  const float* hidden = (const float*)d_in[0];
  const int* positions = (const int*)d_in[1];
  const float* Wq = (const float*)d_in[2];
  const float* Wk = (const float*)d_in[3];
  const float* Wv = (const float*)d_in[4];
  const float* Wo = (const float*)d_in[5];
  const float* qw = (const float*)d_in[6];
  const float* kw = (const float*)d_in[7];
  float* out = (float*)d_out;

  // 64 MB workspace layout:
  char* ws = (char*)d_ws;
  ushort_t* Xbf = (ushort_t*)(ws);                    // 16 MB (4096x2048 bf16)
  ushort_t* WqkvT = (ushort_t*)(ws + (16l << 20));    // 12 MB (3072x2048 bf16)
  ushort_t* WoT = (ushort_t*)(ws + (28l << 20));      //  8 MB (2048x2048 bf16)
  ushort_t* qkvb = (ushort_t*)(ws + (36l << 20));     // 24 MB (4096x3072 bf16)
  ushort_t* Vt = (ushort_t*)(ws + (60l << 20));       //  4 MB (B,NKV,D,S bf16)
  ushort_t* ctx = Xbf;                                // reuse (dead after GEMM1)

  prep_inputs<<<14336, 256, 0, stream>>>(hidden, Xbf, Wq, Wk, Wv, Wo, WqkvT, WoT);

  // GEMM1 on the 8-phase 256^2 kernel: grid 12x16 = 192 blocks (%8==0)
  gemm256_bt<ushort_t><<<dim3(3072 / 256, 4096 / 256), 512, 0, stream>>>(Xbf, WqkvT, qkvb, 4096, 3072, 2048);

  rmsnorm_rope_tv<<<20480 + 512, 256, 0, stream>>>(qkvb, positions, qw, kw, Vt);

  flash_attn<<<dim3(Ss / 128, NH, Bb), 512, 0, stream>>>(qkvb, Vt, ctx);

  gemm_bt<float><<<dim3(2048 / 128, 4096 / 128), 256, 0, stream>>>(ctx, WoT, out, 4096, 2048, 2048);
}